// Round 7
// baseline (4376.284 us; speedup 1.0000x reference)
//
#include <hip/hip_runtime.h>

#define EPS_BN 1e-5f

typedef unsigned int u32;
typedef short short8 __attribute__((ext_vector_type(8)));
typedef float f32x16 __attribute__((ext_vector_type(16)));

constexpr int N_IN_C  = 100000;
constexpr int N_OUT_C = 400000;
constexpr int KTAPS   = 27;
constexpr int M_UP_C  = 100000;
constexpr int M_C_C   = 120000;

constexpr int OTILE   = 128;                    // phase-B output tile rows
constexpr int NTILES  = N_OUT_C / OTILE;        // 3125
constexpr int NBB     = NTILES * KTAPS;         // 84375 out-sort buckets
constexpr int NWIN_U  = (N_IN_C  + 255) / 256;  // 391
constexpr int NWIN_C  = (N_OUT_C + 511) / 512;  // 782
constexpr int NBA_U   = NWIN_U * KTAPS;         // 10557
constexpr int NBA_C   = NWIN_C * KTAPS;         // 21114
constexpr int MAXPAIR = KTAPS * M_C_C;          // 3.24M
constexpr int ENTCAP  = MAXPAIR + NBA_C * 31;   // padded A-entries cap

__device__ inline unsigned short f2bf(float f) {
    u32 u = __builtin_bit_cast(u32, f);
    return (unsigned short)((u + 0x7FFFu + ((u >> 16) & 1u)) >> 16);
}
__device__ inline float bf2f(unsigned short u) {
    return __builtin_bit_cast(float, (u32)u << 16);
}

// ---------------------------------------------------------------------------
// Pack weights into MFMA B-fragment layout, bf16.
// frag[tap][f][lane][j] = W[tap][k = 16f + 8*(lane>>5) + j][lane&31]
// ---------------------------------------------------------------------------
__global__ __launch_bounds__(256) void wpack_kernel(
    const float* __restrict__ wU, const float* __restrict__ w1,
    const float* __restrict__ w2,
    ushort* __restrict__ fU, ushort* __restrict__ f1, ushort* __restrict__ f2)
{
    const int t = blockIdx.x * 256 + threadIdx.x;
    const float* w; ushort* dst; int CIN, NF, local;
    if      (t <  6912) { w = wU; dst = fU; CIN = 64; NF = 4; local = t; }
    else if (t < 13824) { w = w1; dst = f1; CIN = 64; NF = 4; local = t - 6912; }
    else if (t < 17280) { w = w2; dst = f2; CIN = 32; NF = 2; local = t - 13824; }
    else return;
    const int lane = local & 63;
    const int fi   = (local >> 6) % NF;
    const int tap  = local / (64 * NF);
    const int half = lane >> 5, colc = lane & 31;
    ushort* o = dst + ((size_t)(tap * NF + fi) * 64 + lane) * 8;
#pragma unroll
    for (int j = 0; j < 8; ++j) {
        const int k = 16 * fi + 8 * half + j;
        o[j] = f2bf(w[((size_t)tap * CIN + k) * 32 + colc]);
    }
}

// ---------------------------------------------------------------------------
// Fused dual histogram: out-buckets (o>>7)*27+k and in-buckets (in>>SH)*27+k.
// ---------------------------------------------------------------------------
template <int SH>
__global__ __launch_bounds__(256) void histAB_kernel(
    const int* __restrict__ out_idx, const int* __restrict__ in_idx,
    u32* __restrict__ cntB, u32* __restrict__ cntA, int M)
{
    const int k = blockIdx.y;
    const int m = blockIdx.x * 256 + threadIdx.x;
    if (m >= M) return;
    const int o  = out_idx[(size_t)k * M + m];
    const int in = in_idx[(size_t)k * M + m];
    atomicAdd(&cntB[(o >> 7) * KTAPS + k], 1u);
    atomicAdd(&cntA[(in >> SH) * KTAPS + k], 1u);
}

// ---------------------------------------------------------------------------
// Single-block exclusive scan; PAD32 rounds each bucket up to a 32-multiple.
// ---------------------------------------------------------------------------
template <bool PAD32>
__global__ __launch_bounds__(1024) void scan_kernel(
    const u32* __restrict__ cnt, u32* __restrict__ starts,
    u32* __restrict__ cursor, int nb)
{
    __shared__ u32 part[1024];
    const int t = threadIdx.x;
    const int per = (nb + 1023) >> 10;
    const int b0 = min(t * per, nb);
    const int b1 = min(b0 + per, nb);
    u32 s = 0;
    for (int i = b0; i < b1; ++i)
        s += PAD32 ? ((cnt[i] + 31u) & ~31u) : cnt[i];
    part[t] = s;
    __syncthreads();
    for (int off = 1; off < 1024; off <<= 1) {
        const u32 v = (t >= off) ? part[t - off] : 0u;
        __syncthreads();
        part[t] += v;
        __syncthreads();
    }
    u32 run = t ? part[t - 1] : 0u;
    for (int i = b0; i < b1; ++i) {
        starts[i] = run; cursor[i] = run;
        run += PAD32 ? ((cnt[i] + 31u) & ~31u) : cnt[i];
    }
    if (t == 1023) starts[nb] = run;
}

// ---------------------------------------------------------------------------
// Fused fill: out-rank gives pos (product slot + phase-B order) and writes
// outlo[pos]; in-rank writes entryA = (in&WINM)<<22 | pos.
// ---------------------------------------------------------------------------
template <int SH, int WINM>
__global__ __launch_bounds__(256) void fillAB_kernel(
    const int* __restrict__ out_idx, const int* __restrict__ in_idx,
    u32* __restrict__ curB, u32* __restrict__ curA,
    unsigned char* __restrict__ outlo, u32* __restrict__ entryA, int M)
{
    const int k = blockIdx.y;
    const int m = blockIdx.x * 256 + threadIdx.x;
    if (m >= M) return;
    const int o  = out_idx[(size_t)k * M + m];
    const int in = in_idx[(size_t)k * M + m];
    const u32 pos = atomicAdd(&curB[(o >> 7) * KTAPS + k], 1u);
    outlo[pos] = (unsigned char)(o & 127);
    const u32 pA = atomicAdd(&curA[(in >> SH) * KTAPS + k], 1u);
    entryA[pA] = ((u32)(in & WINM) << 22) | pos;
}

// ---------------------------------------------------------------------------
// Phase A: one block per input window. Stage window rows into LDS (bf16,
// XOR-swizzled 16B chunks), then tap-pure MFMA batches gather A-fragments
// from LDS and write each pair's 32-ch bf16 product row to prod[pos]
// (random 64-B global write, fire-and-forget).
// MODE 0: up   (srcA = x fp32, 64ch)
// MODE 1: conv1(srcA = h16 bf16 32ch, srcB = x_skip fp32 32ch)
// MODE 2: conv2(srcA = h16 bf16 32ch)
// ---------------------------------------------------------------------------
template <int NF, int MODE, int WIN>
__global__ __launch_bounds__(256) void phaseA_kernel(
    const void* __restrict__ srcAv, const void* __restrict__ srcBv,
    const ushort* __restrict__ wfrag,
    const u32* __restrict__ entryA, const u32* __restrict__ startsA,
    ushort* __restrict__ prod, int n_src)
{
    constexpr int NCH = NF * 2;        // 16B chunks per row
    constexpr int RPL = 8 / NCH;       // rows per 128B super-row (1 or 2)
    __shared__ ushort win[WIN * NF * 16];

    const int w0   = blockIdx.x * WIN;
    const int tid  = threadIdx.x;
    const int lane = tid & 63;
    const int wid  = tid >> 6;
    const int col  = lane & 31;
    const int half = lane >> 5;

    // ---- stage window (sequential global reads, swizzled LDS writes) ----
    for (int i = tid; i < WIN * NCH; i += 256) {
        const int r  = i / NCH, ch = i % NCH;
        const int row = w0 + r;
        short8 v = {0, 0, 0, 0, 0, 0, 0, 0};
        if (row < n_src) {
            if (MODE == 0) {
                const float* s = (const float*)srcAv + (size_t)row * 64 + ch * 8;
#pragma unroll
                for (int j = 0; j < 8; ++j) v[j] = (short)f2bf(s[j]);
            } else if (MODE == 1) {
                if (ch < 4) {
                    v = *reinterpret_cast<const short8*>(
                        (const ushort*)srcAv + (size_t)row * 32 + ch * 8);
                } else {
                    const float* s = (const float*)srcBv + (size_t)row * 32 + (ch - 4) * 8;
#pragma unroll
                    for (int j = 0; j < 8; ++j) v[j] = (short)f2bf(s[j]);
                }
            } else {
                v = *reinterpret_cast<const short8*>(
                    (const ushort*)srcAv + (size_t)row * 32 + ch * 8);
            }
        }
        const int addr = (r / RPL) * 64 + ((((r % RPL) * NCH + ch) ^ ((r / RPL) & 7)) * 8);
        *reinterpret_cast<short8*>(&win[addr]) = v;
    }
    __syncthreads();

    const short8* wf8 = reinterpret_cast<const short8*>(wfrag);

    for (int tap = wid; tap < KTAPS; tap += 4) {
        short8 bf[NF];
#pragma unroll
        for (int f = 0; f < NF; ++f) bf[f] = wf8[(tap * NF + f) * 64 + lane];

        const int b  = blockIdx.x * KTAPS + tap;
        const int s0 = (int)startsA[b];
        const int s1 = (int)startsA[b + 1];

        for (int bb = s0; bb < s1; bb += 32) {
            const u32 e   = entryA[bb + col];
            const int r   = (int)(e >> 22) & (WIN - 1);
            const u32 pos = e & 0x3FFFFFu;

            short8 af[NF];
#pragma unroll
            for (int f = 0; f < NF; ++f) {
                const int ch   = f * 2 + half;
                const int addr = (r / RPL) * 64 +
                                 ((((r % RPL) * NCH + ch) ^ ((r / RPL) & 7)) * 8);
                af[f] = *reinterpret_cast<const short8*>(&win[addr]);
            }

            f32x16 acc;
#pragma unroll
            for (int rr = 0; rr < 16; ++rr) acc[rr] = 0.f;
#pragma unroll
            for (int f = 0; f < NF; ++f)
                acc = __builtin_amdgcn_mfma_f32_32x32x16_bf16(af[f], bf[f], acc, 0, 0, 0);

#pragma unroll
            for (int rr = 0; rr < 16; ++rr) {
                const int prow = (rr & 3) + 8 * (rr >> 2) + 4 * half;
                const u32 p    = (u32)__shfl((int)pos, prow);
                if (p != 0x3FFFFFu)
                    prod[(size_t)p * 32 + col] = f2bf(acc[rr]);
            }
        }
    }
}

// ---------------------------------------------------------------------------
// Phase B: one block per 128-row output tile. Sequentially read the tile's
// product segment (out-sorted), ds_add into a stride-33 LDS tile, then
// coalesced write + fused BN partial stats.
// ---------------------------------------------------------------------------
__global__ __launch_bounds__(256) void phaseB_kernel(
    const ushort* __restrict__ prod, const unsigned char* __restrict__ outlo,
    const u32* __restrict__ startsB,
    float* __restrict__ dest, float* __restrict__ stats)
{
    __shared__ float sacc[OTILE * 33];
    const int tile = blockIdx.x;
    const int tid  = threadIdx.x;
    const int lane = tid & 63;
    const int wid  = tid >> 6;

    for (int i = tid; i < OTILE * 33; i += 256) sacc[i] = 0.f;
    __syncthreads();

    const int s0 = (int)startsB[tile * KTAPS];
    const int s1 = (int)startsB[tile * KTAPS + KTAPS];
    const int p  = lane >> 3;    // pair slot 0..7 within wave
    const int s  = lane & 7;     // 4-channel segment 0..7

    for (int base = s0 + wid * 8; base < s1; base += 32) {
        const int i = base + p;
        if (i < s1) {
            const short4 v  = *reinterpret_cast<const short4*>(&prod[(size_t)i * 32 + s * 4]);
            const int    row = (int)outlo[i];
            float* dst = &sacc[row * 33 + s * 4];
            atomicAdd(dst + 0, bf2f((unsigned short)v.x));
            atomicAdd(dst + 1, bf2f((unsigned short)v.y));
            atomicAdd(dst + 2, bf2f((unsigned short)v.z));
            atomicAdd(dst + 3, bf2f((unsigned short)v.w));
        }
    }
    __syncthreads();

    const int row0 = tile * OTILE;
    float sm = 0.f, qm = 0.f;
    for (int i = tid; i < OTILE * 32; i += 256) {
        const float v = sacc[(i >> 5) * 33 + (i & 31)];
        dest[(size_t)row0 * 32 + i] = v;
        sm += v;
        qm = fmaf(v, v, qm);
    }
    __syncthreads();
    sacc[tid]       = sm;
    sacc[256 + tid] = qm;
    __syncthreads();
    if (tid < 32) {
        float ts = 0.f, tq = 0.f;
#pragma unroll
        for (int g = 0; g < 8; ++g) {
            ts += sacc[tid + 32 * g];
            tq += sacc[256 + tid + 32 * g];
        }
        atomicAdd(&stats[tid], ts);
        atomicAdd(&stats[32 + tid], tq);
    }
}

// ---------------------------------------------------------------------------
// y = relu((x-mean)*rsqrt(var+eps)*g + bt); dst bf16 (intermediate) or f32.
// ---------------------------------------------------------------------------
template <bool BF16OUT>
__global__ __launch_bounds__(256) void bn_relu_kernel(
    const float* __restrict__ h,
    const float* __restrict__ stats,
    const float* __restrict__ g,
    const float* __restrict__ bt,
    void* __restrict__ dst, int n)
{
    const int i = blockIdx.x * 256 + threadIdx.x;
    if (i >= n * 8) return;
    const float4 v = reinterpret_cast<const float4*>(h)[i];
    const int c0 = (i & 7) * 4;
    const float invn = 1.f / (float)n;
    float o[4];
    const float vin[4] = {v.x, v.y, v.z, v.w};
#pragma unroll
    for (int j = 0; j < 4; ++j) {
        const int c   = c0 + j;
        const float m   = stats[c] * invn;
        const float var = fmaxf(stats[32 + c] * invn - m * m, 0.f);
        const float sc  = rsqrtf(var + EPS_BN) * g[c];
        float y = (vin[j] - m) * sc + bt[c];
        o[j] = y > 0.f ? y : 0.f;
    }
    if (BF16OUT) {
        ushort4 w;
        w.x = f2bf(o[0]); w.y = f2bf(o[1]); w.z = f2bf(o[2]); w.w = f2bf(o[3]);
        reinterpret_cast<ushort4*>(dst)[i] = w;
    } else {
        float4 w = {o[0], o[1], o[2], o[3]};
        reinterpret_cast<float4*>(dst)[i] = w;
    }
}

// ---------------------------------------------------------------------------
extern "C" void kernel_launch(void* const* d_in, const int* in_sizes, int n_in,
                              void* d_out, int out_size, void* d_ws, size_t ws_size,
                              hipStream_t stream)
{
    const float* x      = (const float*)d_in[0];
    const float* x_skip = (const float*)d_in[1];
    const float* w_up   = (const float*)d_in[2];
    // d_in[3] = b_up cancels exactly through train-mode BN -> unused.
    const float* g_up   = (const float*)d_in[4];
    const float* bt_up  = (const float*)d_in[5];
    const float* w1     = (const float*)d_in[6];
    const float* g1     = (const float*)d_in[7];
    const float* bt1    = (const float*)d_in[8];
    const float* w2     = (const float*)d_in[9];
    const float* g2     = (const float*)d_in[10];
    const float* bt2    = (const float*)d_in[11];
    const int* up_in    = (const int*)d_in[12];
    const int* up_out   = (const int*)d_in[13];
    const int* c1_in    = (const int*)d_in[14];
    const int* c1_out   = (const int*)d_in[15];
    const int* c2_in    = (const int*)d_in[16];
    const int* c2_out   = (const int*)d_in[17];

    // ---- workspace carve ----
    char* p = (char*)d_ws;
    auto alloc = [&](size_t bytes) { char* r = p; p += (bytes + 255) & ~(size_t)255; return r; };
    ushort* h16    = (ushort*)alloc((size_t)N_OUT_C * 32 * 2);       // 25.6 MB
    ushort* wfU    = (ushort*)alloc(27 * 4 * 64 * 8 * 2);
    ushort* wf1    = (ushort*)alloc(27 * 4 * 64 * 8 * 2);
    ushort* wf2    = (ushort*)alloc(27 * 2 * 64 * 8 * 2);
    float*  stats  = (float*) alloc(192 * 4);
    u32*    cntB   = (u32*)   alloc((size_t)(NBB + NBA_C) * 4);      // cntB | cntA contiguous
    u32*    cntA   = cntB + NBB;
    u32*    startsB= (u32*)   alloc((size_t)(NBB + 1) * 4);
    u32*    curB   = (u32*)   alloc((size_t)NBB * 4);
    u32*    startsA= (u32*)   alloc((size_t)(NBA_C + 1) * 4);
    u32*    curA   = (u32*)   alloc((size_t)NBA_C * 4);
    unsigned char* outlo = (unsigned char*)alloc(MAXPAIR);
    u32*    entryA = (u32*)   alloc((size_t)ENTCAP * 4);             // 15.6 MB
    ushort* prod   = (ushort*)alloc((size_t)MAXPAIR * 32 * 2);       // 207.4 MB

    float* out = (float*)d_out;
    const dim3 blk(256);
    const dim3 gUp((M_UP_C + 255) / 256, KTAPS);
    const dim3 gC ((M_C_C  + 255) / 256, KTAPS);
    const int bn_blocks = (N_OUT_C * 8 + 255) / 256;

    hipMemsetAsync(stats, 0, 192 * sizeof(float), stream);
    wpack_kernel<<<(17280 + 255) / 256, blk, 0, stream>>>(w_up, w1, w2, wfU, wf1, wf2);

    // ================= stage 1: up conv (x fp32 64ch -> out raw) ==========
    hipMemsetAsync(cntB, 0, (size_t)(NBB + NBA_C) * 4, stream);
    hipMemsetAsync(entryA, 0xFF, (size_t)ENTCAP * 4, stream);
    histAB_kernel<8><<<gUp, blk, 0, stream>>>(up_out, up_in, cntB, cntA, M_UP_C);
    scan_kernel<false><<<1, 1024, 0, stream>>>(cntB, startsB, curB, NBB);
    scan_kernel<true ><<<1, 1024, 0, stream>>>(cntA, startsA, curA, NBA_U);
    fillAB_kernel<8, 255><<<gUp, blk, 0, stream>>>(up_out, up_in, curB, curA,
                                                   outlo, entryA, M_UP_C);
    phaseA_kernel<4, 0, 256><<<NWIN_U, blk, 0, stream>>>(
        x, nullptr, wfU, entryA, startsA, prod, N_IN_C);
    phaseB_kernel<<<NTILES, blk, 0, stream>>>(prod, outlo, startsB, out, stats);
    bn_relu_kernel<true><<<bn_blocks, blk, 0, stream>>>(out, stats, g_up, bt_up, h16, N_OUT_C);

    // ================= stage 2: conv1 (h16 bf16 | x_skip fp32) ============
    hipMemsetAsync(cntB, 0, (size_t)(NBB + NBA_C) * 4, stream);
    hipMemsetAsync(entryA, 0xFF, (size_t)ENTCAP * 4, stream);
    histAB_kernel<9><<<gC, blk, 0, stream>>>(c1_out, c1_in, cntB, cntA, M_C_C);
    scan_kernel<false><<<1, 1024, 0, stream>>>(cntB, startsB, curB, NBB);
    scan_kernel<true ><<<1, 1024, 0, stream>>>(cntA, startsA, curA, NBA_C);
    fillAB_kernel<9, 511><<<gC, blk, 0, stream>>>(c1_out, c1_in, curB, curA,
                                                  outlo, entryA, M_C_C);
    phaseA_kernel<4, 1, 512><<<NWIN_C, blk, 0, stream>>>(
        h16, x_skip, wf1, entryA, startsA, prod, N_OUT_C);
    phaseB_kernel<<<NTILES, blk, 0, stream>>>(prod, outlo, startsB, out, stats + 64);
    bn_relu_kernel<true><<<bn_blocks, blk, 0, stream>>>(out, stats + 64, g1, bt1, h16, N_OUT_C);

    // ================= stage 3: conv2 (h16 bf16 32ch) =====================
    hipMemsetAsync(cntB, 0, (size_t)(NBB + NBA_C) * 4, stream);
    hipMemsetAsync(entryA, 0xFF, (size_t)ENTCAP * 4, stream);
    histAB_kernel<9><<<gC, blk, 0, stream>>>(c2_out, c2_in, cntB, cntA, M_C_C);
    scan_kernel<false><<<1, 1024, 0, stream>>>(cntB, startsB, curB, NBB);
    scan_kernel<true ><<<1, 1024, 0, stream>>>(cntA, startsA, curA, NBA_C);
    fillAB_kernel<9, 511><<<gC, blk, 0, stream>>>(c2_out, c2_in, curB, curA,
                                                  outlo, entryA, M_C_C);
    phaseA_kernel<2, 2, 512><<<NWIN_C, blk, 0, stream>>>(
        h16, nullptr, wf2, entryA, startsA, prod, N_OUT_C);
    phaseB_kernel<<<NTILES, blk, 0, stream>>>(prod, outlo, startsB, out, stats + 128);
    bn_relu_kernel<false><<<bn_blocks, blk, 0, stream>>>(out, stats + 128, g2, bt2, out, N_OUT_C);
}